// Round 9
// baseline (151.767 us; speedup 1.0000x reference)
//
#include <hip/hip_runtime.h>

using f32x4 = __attribute__((ext_vector_type(4))) float;
using f32x2 = __attribute__((ext_vector_type(2))) float;
using bf16x8 = __attribute__((ext_vector_type(8))) short;

#define MFMA(a, b, c) __builtin_amdgcn_mfma_f32_16x16x32_bf16(a, b, c, 0, 0, 0)

__device__ __forceinline__ unsigned short f2bf(float f) {
    union { float f; unsigned u; } c; c.f = f;
    unsigned u = c.u;
    u += 0x7fffu + ((u >> 16) & 1u);
    return (unsigned short)(u >> 16);
}
__device__ __forceinline__ float bf2f(unsigned short s) {
    union { unsigned u; float f; } c; c.u = ((unsigned)s) << 16; return c.f;
}
// HW packed f32x2 -> bf16x2 (RNE), 1 instruction vs ~8 VALU ops for 2x f2bf.
__device__ __forceinline__ unsigned cvtpk(float lo, float hi) {
    unsigned r;
    asm("v_cvt_pk_bf16_f32 %0, %1, %2" : "=v"(r) : "v"(lo), "v"(hi));
    return r;
}
__device__ __forceinline__ unsigned pack2(float a, float b) { return cvtpk(a, b); }
__device__ __forceinline__ bf16x8 pk8(f32x4 a, f32x4 b) {
    union { unsigned u[4]; bf16x8 v; } r;
    r.u[0] = cvtpk(a[0], a[1]); r.u[1] = cvtpk(a[2], a[3]);
    r.u[2] = cvtpk(b[0], b[1]); r.u[3] = cvtpk(b[2], b[3]);
    return r.v;
}

// ---------------------------------------------------------------------------
// K1: q/k/v projections. q scaled 0.125. q,k -> bf16 [1024][512]; v -> vt.
// ---------------------------------------------------------------------------
__global__ __launch_bounds__(256) void k_qkv(
    const float* __restrict__ nodes,
    const float* __restrict__ Wq, const float* __restrict__ bq,
    const float* __restrict__ Wk, const float* __restrict__ bk,
    const float* __restrict__ Wv, const float* __restrict__ bv,
    unsigned short* __restrict__ qbf, unsigned short* __restrict__ kbf,
    unsigned short* __restrict__ vt)
{
    const int kind = blockIdx.z;
    const float* W = (kind == 0) ? Wq : ((kind == 1) ? Wk : Wv);
    const float* bias = (kind == 0) ? bq : ((kind == 1) ? bk : bv);
    const int i0 = blockIdx.x * 64, n0 = blockIdx.y * 64;
    const int t = threadIdx.x, lane = t & 63, w = t >> 6;
    const int l15 = lane & 15, l4 = lane >> 4;
    __shared__ __align__(16) unsigned short sA[64 * 72];
    __shared__ __align__(16) unsigned short sB[64 * 72];
    f32x4 acc[2][2] = {};
    const int wr = (w >> 1) * 32, wc = (w & 1) * 32;
    const int r = t >> 2, q4 = t & 3;
    for (int kb = 0; kb < 512; kb += 64) {
        for (int k = 0; k < 4; k++) {
            int col = k * 16 + q4 * 4;
            f32x4 av = *(const f32x4*)(nodes + (i0 + r) * 512 + kb + col);
            f32x4 bv_ = *(const f32x4*)(W + (n0 + r) * 512 + kb + col);
            uint2 pa; pa.x = pack2(av.x, av.y); pa.y = pack2(av.z, av.w);
            uint2 pb; pb.x = pack2(bv_.x, bv_.y); pb.y = pack2(bv_.z, bv_.w);
            *(uint2*)(sA + r * 72 + col) = pa;
            *(uint2*)(sB + r * 72 + col) = pb;
        }
        __syncthreads();
        for (int ks = 0; ks < 2; ks++) {
            bf16x8 a0 = *(const bf16x8*)(sA + (wr + l15) * 72 + ks * 32 + l4 * 8);
            bf16x8 a1 = *(const bf16x8*)(sA + (wr + 16 + l15) * 72 + ks * 32 + l4 * 8);
            bf16x8 b0 = *(const bf16x8*)(sB + (wc + l15) * 72 + ks * 32 + l4 * 8);
            bf16x8 b1 = *(const bf16x8*)(sB + (wc + 16 + l15) * 72 + ks * 32 + l4 * 8);
            acc[0][0] = MFMA(a0, b0, acc[0][0]);
            acc[0][1] = MFMA(a0, b1, acc[0][1]);
            acc[1][0] = MFMA(a1, b0, acc[1][0]);
            acc[1][1] = MFMA(a1, b1, acc[1][1]);
        }
        __syncthreads();
    }
    const float scale = (kind == 0) ? 0.125f : 1.0f;
    for (int fi = 0; fi < 2; fi++) for (int fj = 0; fj < 2; fj++)
        for (int rr = 0; rr < 4; rr++) {
            int i = i0 + wr + fi * 16 + l4 * 4 + rr;
            int n = n0 + wc + fj * 16 + l15;
            float v = (acc[fi][fj][rr] + bias[n]) * scale;
            if (kind == 0) qbf[i * 512 + n] = f2bf(v);
            else if (kind == 1) kbf[i * 512 + n] = f2bf(v);
            else vt[n * 1024 + i] = f2bf(v);
        }
}

// ---------------------------------------------------------------------------
// K1b: U[i][h*64+e] = sum_d q[i][h*64+d] * Wsk[d][e]   (bf16 out)
// ---------------------------------------------------------------------------
__global__ __launch_bounds__(256) void k_u(
    const unsigned short* __restrict__ qbf, const float* __restrict__ Wsk,
    unsigned short* __restrict__ U)
{
    const int i0 = blockIdx.x * 64, h = blockIdx.y;
    const int t = threadIdx.x, lane = t & 63, w = t >> 6;
    const int l15 = lane & 15, l4 = lane >> 4;
    __shared__ __align__(16) unsigned short sQ[64 * 72];
    __shared__ __align__(16) unsigned short sWT[64 * 72];   // Wsk^T bf16 [e][d]
    {
        const int r = t >> 2, c0 = (t & 3) * 16;
        *(uint4*)(sQ + r * 72 + c0) = *(const uint4*)(qbf + (i0 + r) * 512 + h * 64 + c0);
        *(uint4*)(sQ + r * 72 + c0 + 8) = *(const uint4*)(qbf + (i0 + r) * 512 + h * 64 + c0 + 8);
        #pragma unroll
        for (int e = 0; e < 16; e++)
            sWT[(c0 + e) * 72 + r] = f2bf(Wsk[r * 64 + c0 + e]);
    }
    __syncthreads();
    bf16x8 b0 = *(const bf16x8*)(sWT + (w * 16 + l15) * 72 + l4 * 8);
    bf16x8 b1 = *(const bf16x8*)(sWT + (w * 16 + l15) * 72 + 32 + l4 * 8);
    for (int fb = 0; fb < 4; fb++) {
        bf16x8 a0 = *(const bf16x8*)(sQ + (fb * 16 + l15) * 72 + l4 * 8);
        bf16x8 a1 = *(const bf16x8*)(sQ + (fb * 16 + l15) * 72 + 32 + l4 * 8);
        f32x4 acc; acc[0] = acc[1] = acc[2] = acc[3] = 0.f;
        acc = MFMA(a0, b0, acc); acc = MFMA(a1, b1, acc);
        #pragma unroll
        for (int rr = 0; rr < 4; rr++)
            U[(i0 + fb * 16 + l4 * 4 + rr) * 512 + h * 64 + w * 16 + l15] = f2bf(acc[rr]);
    }
}

// ---------------------------------------------------------------------------
// K2: node-node scores S[h][i][j] (unchanged)
// ---------------------------------------------------------------------------
__global__ __launch_bounds__(256) void k_scores(
    const unsigned short* __restrict__ qbf, const unsigned short* __restrict__ kbf,
    float* __restrict__ S)
{
    const int h = blockIdx.z, i0 = blockIdx.x * 64, j0 = blockIdx.y * 64;
    const int t = threadIdx.x, lane = t & 63, w = t >> 6;
    const int l15 = lane & 15, l4 = lane >> 4;
    __shared__ __align__(16) unsigned short sQ[64 * 72];
    __shared__ __align__(16) unsigned short sK[64 * 72];
    const int r = t >> 2, q4 = t & 3;
    for (int k = 0; k < 2; k++) {
        int col = k * 32 + q4 * 8;
        uint4 aq = *(const uint4*)(qbf + (i0 + r) * 512 + h * 64 + col);
        uint4 ak = *(const uint4*)(kbf + (j0 + r) * 512 + h * 64 + col);
        *(uint4*)(sQ + r * 72 + col) = aq;
        *(uint4*)(sK + r * 72 + col) = ak;
    }
    __syncthreads();
    f32x4 acc[2][2] = {};
    const int wr = (w >> 1) * 32, wc = (w & 1) * 32;
    for (int ks = 0; ks < 2; ks++) {
        bf16x8 a0 = *(const bf16x8*)(sQ + (wr + l15) * 72 + ks * 32 + l4 * 8);
        bf16x8 a1 = *(const bf16x8*)(sQ + (wr + 16 + l15) * 72 + ks * 32 + l4 * 8);
        bf16x8 b0 = *(const bf16x8*)(sK + (wc + l15) * 72 + ks * 32 + l4 * 8);
        bf16x8 b1 = *(const bf16x8*)(sK + (wc + 16 + l15) * 72 + ks * 32 + l4 * 8);
        acc[0][0] = MFMA(a0, b0, acc[0][0]);
        acc[0][1] = MFMA(a0, b1, acc[0][1]);
        acc[1][0] = MFMA(a1, b0, acc[1][0]);
        acc[1][1] = MFMA(a1, b1, acc[1][1]);
    }
    for (int fi = 0; fi < 2; fi++) for (int fj = 0; fj < 2; fj++)
        for (int rr = 0; rr < 4; rr++) {
            long i = i0 + wr + fi * 16 + l4 * 4 + rr;
            int j = j0 + wc + fj * 16 + l15;
            S[((long)h << 20) + i * 1024 + j] = acc[fi][fj][rr];
        }
}

// ---------------------------------------------------------------------------
// K3 v9: barrier-free fused attention core (v7 structure + LN params in LDS).
// NO VGPR cap (R8's __launch_bounds__(256,4) cap broke correctness; the LDS
// demotion alone should drop natural VGPR use toward <=128).
// ---------------------------------------------------------------------------
__global__ __launch_bounds__(256) void k_attn(
    const float* __restrict__ edges, const int* __restrict__ maskp,
    const float* __restrict__ S, const unsigned short* __restrict__ qbf,
    const unsigned short* __restrict__ Ubf,
    const float* __restrict__ bsk, const float* __restrict__ Wsv,
    const float* __restrict__ bsv,
    const float* __restrict__ png, const float* __restrict__ pnb,
    unsigned short* __restrict__ P, float* __restrict__ Mt,
    float* __restrict__ Ml, float* __restrict__ outs)
{
    const int i = blockIdx.x;
    const int t = threadIdx.x;
    const int lane = t & 63, w = t >> 6;
    const int l15 = lane & 15, l4 = lane >> 4;
    const int ecol = l4 * 8;

    __shared__ __align__(16) unsigned short s_wsv[64 * 72];   // 9216 B
    __shared__ __align__(16) unsigned short s_svt[4][64 * 40];// 20480 B
    __shared__ __align__(16) unsigned short s_p8[4][16 * 40]; // 5120 B
    __shared__ float s_g[64], s_b[64];                        // 512 B
    __shared__ float s_mw[32], s_lw[32], s_mf[8], s_lf[8], s_qbsk[8];

    unsigned short* svtw = s_svt[w];
    unsigned short* p8w = s_p8[w];

    // ---- stage Wsv as bf16 in LDS; LN params as f32 in LDS
    {
        const int row = t >> 2, c0 = (t & 3) * 16;
        const float* pv = Wsv + row * 64 + c0;
        uint2 w0, w1;
        w0.x = pack2(pv[0], pv[1]);  w0.y = pack2(pv[2], pv[3]);
        w1.x = pack2(pv[4], pv[5]);  w1.y = pack2(pv[6], pv[7]);
        *(uint2*)(s_wsv + row * 72 + c0) = w0;
        *(uint2*)(s_wsv + row * 72 + c0 + 4) = w1;
        w0.x = pack2(pv[8], pv[9]);  w0.y = pack2(pv[10], pv[11]);
        w1.x = pack2(pv[12], pv[13]); w1.y = pack2(pv[14], pv[15]);
        *(uint2*)(s_wsv + row * 72 + c0 + 8) = w0;
        *(uint2*)(s_wsv + row * 72 + c0 + 12) = w1;
    }
    if (t < 64) { s_g[t] = png[t]; s_b[t] = pnb[t]; }
    // ---- zero p8 rows 8-15 of every wave buffer (never rewritten)
    {
        int wb = t >> 6, rem = t & 63;
        int row = 8 + (rem >> 3), c4 = (rem & 7) * 4;
        uint2 z; z.x = 0; z.y = 0;
        *(uint2*)(&s_p8[wb][row * 40 + c4]) = z;
    }
    if (t < 8) {
        float a = 0.f;
        for (int d = 0; d < 64; d++) a += bf2f(qbf[i * 512 + t * 64 + d]) * bsk[d];
        s_qbsk[t] = a;
    }

    // ---- U A-fragment: rows = heads (l15<8), rows 8-15 zero
    bf16x8 aU0 = {}, aU1 = {};
    if (l15 < 8) {
        aU0 = *(const bf16x8*)(Ubf + i * 512 + l15 * 64 + ecol);
        aU1 = *(const bf16x8*)(Ubf + i * 512 + l15 * 64 + 32 + ecol);
    }

    __syncthreads();   // weights / LN params / p8-zeros / qbsk visible

    const int hc = (l4 & 1) * 4;   // this lane's 4 heads (lanes 32-63 mirror)
    float qb[4];
    #pragma unroll
    for (int rr = 0; rr < 4; rr++) qb[rr] = s_qbsk[hc + rr];

    const float* erow = edges + (long)i * 65536;
    f32x4 m_run, l_run;
    #pragma unroll
    for (int rr = 0; rr < 4; rr++) { m_run[rr] = -1e30f; l_run[rr] = 0.f; }
    f32x4 acc[4] = {};

    for (int it = 0; it < 8; it++) {
        const int jt = w * 256 + it * 32;
        const float* pa = erow + (jt + l15) * 64 + ecol;
        const float* pb = pa + 16 * 64;
        f32x4 ea0 = *(const f32x4*)(pa);
        f32x4 ea1 = *(const f32x4*)(pa + 4);
        f32x4 ea2 = *(const f32x4*)(pa + 32);
        f32x4 ea3 = *(const f32x4*)(pa + 36);
        f32x4 eb0 = *(const f32x4*)(pb);
        f32x4 eb1 = *(const f32x4*)(pb + 4);
        f32x4 eb2 = *(const f32x4*)(pb + 32);
        f32x4 eb3 = *(const f32x4*)(pb + 36);
        const int jga = jt + l15, jgb = jga + 16;
        float Sva[4], Svb[4];
        #pragma unroll
        for (int rr = 0; rr < 4; rr++) {
            Sva[rr] = S[((long)(hc + rr) << 20) + (long)i * 1024 + jga];
            Svb[rr] = S[((long)(hc + rr) << 20) + (long)i * 1024 + jgb];
        }
        const int mka = maskp[i * 1024 + jga];
        const int mkb = maskp[i * 1024 + jgb];

        f32x4 ca, cb;
        // ===== half A (j = jt .. jt+15) =====
        {
            float s1 = 0.f, s2 = 0.f;
            #pragma unroll
            for (int q = 0; q < 4; q++) {
                s1 += ea0[q] + ea1[q] + ea2[q] + ea3[q];
                s2 += ea0[q]*ea0[q] + ea1[q]*ea1[q] + ea2[q]*ea2[q] + ea3[q]*ea3[q];
            }
            s1 += __shfl_xor(s1, 16); s2 += __shfl_xor(s2, 16);
            s1 += __shfl_xor(s1, 32); s2 += __shfl_xor(s2, 32);
            const float mean = s1 * (1.f / 64.f);
            const float var = s2 * (1.f / 64.f) - mean * mean;
            const float rs = rsqrtf(var + 1e-5f);
            const f32x4 g0 = *(const f32x4*)(s_g + ecol);
            const f32x4 g1 = *(const f32x4*)(s_g + ecol + 4);
            const f32x4 g2 = *(const f32x4*)(s_g + 32 + ecol);
            const f32x4 g3 = *(const f32x4*)(s_g + 36 + ecol);
            const f32x4 b0_ = *(const f32x4*)(s_b + ecol);
            const f32x4 b1_ = *(const f32x4*)(s_b + ecol + 4);
            const f32x4 b2_ = *(const f32x4*)(s_b + 32 + ecol);
            const f32x4 b3_ = *(const f32x4*)(s_b + 36 + ecol);
            f32x4 y0, y1, y2, y3;
            #pragma unroll
            for (int q = 0; q < 4; q++) {
                y0[q] = (ea0[q] - mean) * rs * g0[q] + b0_[q];
                y1[q] = (ea1[q] - mean) * rs * g1[q] + b1_[q];
                y2[q] = (ea2[q] - mean) * rs * g2[q] + b2_[q];
                y3[q] = (ea3[q] - mean) * rs * g3[q] + b3_[q];
            }
            bf16x8 x0 = pk8(y0, y1), x1 = pk8(y2, y3);
            ca[0] = ca[1] = ca[2] = ca[3] = 0.f;
            ca = MFMA(aU0, x0, ca); ca = MFMA(aU1, x1, ca);
            #pragma unroll
            for (int rr = 0; rr < 4; rr++)
                ca[rr] = mka ? (ca[rr] + Sva[rr] + qb[rr]) : -1e9f;
            #pragma unroll
            for (int ob = 0; ob < 4; ob++) {
                bf16x8 wv0 = *(const bf16x8*)(s_wsv + (ob * 16 + l15) * 72 + ecol);
                bf16x8 wv1 = *(const bf16x8*)(s_wsv + (ob * 16 + l15) * 72 + 32 + ecol);
                f32x4 cv; cv[0] = cv[1] = cv[2] = cv[3] = 0.f;
                cv = MFMA(x0, wv0, cv); cv = MFMA(x1, wv1, cv);
                const int jb = l4 * 4;
                *(unsigned*)(svtw + (ob * 16 + l15) * 40 + jb) = pack2(cv[0], cv[1]);
                *(unsigned*)(svtw + (ob * 16 + l15) * 40 + jb + 2) = pack2(cv[2], cv[3]);
            }
        }
        // ===== half B (j = jt+16 .. jt+31) =====
        {
            float s1 = 0.f, s2 = 0.f;
            #pragma unroll
            for (int q = 0; q < 4; q++) {
                s1 += eb0[q] + eb1[q] + eb2[q] + eb3[q];
                s2 += eb0[q]*eb0[q] + eb1[q]*eb1[q] + eb2[q]*eb2[q] + eb3[q]*eb3[q];
            }
            s1 += __shfl_xor(s1, 16); s2 += __shfl_xor(s2, 16);
            s1 += __shfl_xor(s1, 32); s2 += __shfl_xor(s2, 32);
            const float mean = s1 * (1.f / 64.f);
            const float var = s2 * (1.f / 64.f) - mean * mean;
            const float rs = rsqrtf(var + 1e-5f);
            const f32x4 g0 = *(const f32x4*)(s_g + ecol);
            const f32x4 g1 = *(const f32x4*)(s_g + ecol + 4);
            const f32x4 g2 = *(const f32x4*)(s_g + 32 + ecol);
            const f32x4 g3 = *(const f32x4*)(s_g + 36 + ecol);
            const f32x4 b0_ = *(const f32x4*)(s_b + ecol);
            const f32x4 b1_ = *(const f32x4*)(s_b + ecol + 4);
            const f32x4 b2_ = *(const f32x4*)(s_b + 32 + ecol);
            const f32x4 b3_ = *(const f32x4*)(s_b + 36 + ecol);
            f32x4 y0, y1, y2, y3;
            #pragma unroll
            for (int q = 0; q < 4; q++) {
                y0[q] = (eb0[q] - mean) * rs * g0[q] + b0_[q];
                y1[q] = (eb1[q] - mean) * rs * g1[q] + b1_[q];
                y2[q] = (eb2[q] - mean) * rs * g2[q] + b2_[q];
                y3[q] = (eb3[q] - mean) * rs * g3[q] + b3_[q];
            }
            bf16x8 x0 = pk8(y0, y1), x1 = pk8(y2, y3);
            cb[0] = cb[1] = cb[2] = cb[3] = 0.f;
            cb = MFMA(aU0, x0, cb); cb = MFMA(aU1, x1, cb);
            #pragma unroll
            for (int rr = 0; rr < 4; rr++)
                cb[rr] = mkb ? (cb[rr] + Svb[rr] + qb[rr]) : -1e9f;
            #pragma unroll
            for (int ob = 0; ob < 4; ob++) {
                bf16x8 wv0 = *(const bf16x8*)(s_wsv + (ob * 16 + l15) * 72 + ecol);
                bf16x8 wv1 = *(const bf16x8*)(s_wsv + (ob * 16 + l15) * 72 + 32 + ecol);
                f32x4 cv; cv[0] = cv[1] = cv[2] = cv[3] = 0.f;
                cv = MFMA(x0, wv0, cv); cv = MFMA(x1, wv1, cv);
                const int jb = 16 + l4 * 4;
                *(unsigned*)(svtw + (ob * 16 + l15) * 40 + jb) = pack2(cv[0], cv[1]);
                *(unsigned*)(svtw + (ob * 16 + l15) * 40 + jb + 2) = pack2(cv[2], cv[3]);
            }
        }
        // ---- online softmax over this 32-j chunk (wave-local, shfl only)
        f32x4 mx;
        #pragma unroll
        for (int rr = 0; rr < 4; rr++) mx[rr] = fmaxf(ca[rr], cb[rr]);
        for (int m = 1; m < 16; m <<= 1) {
            #pragma unroll
            for (int rr = 0; rr < 4; rr++) mx[rr] = fmaxf(mx[rr], __shfl_xor(mx[rr], m));
        }
        f32x4 mnew, sc;
        #pragma unroll
        for (int rr = 0; rr < 4; rr++) {
            mnew[rr] = fmaxf(m_run[rr], mx[rr]);
            sc[rr] = __expf(m_run[rr] - mnew[rr]);
        }
        f32x4 pA, pB, ps;
        #pragma unroll
        for (int rr = 0; rr < 4; rr++) {
            pA[rr] = __expf(ca[rr] - mnew[rr]);
            pB[rr] = __expf(cb[rr] - mnew[rr]);
            ps[rr] = pA[rr] + pB[rr];
        }
        for (int m = 1; m < 16; m <<= 1) {
            #pragma unroll
            for (int rr = 0; rr < 4; rr++) ps[rr] += __shfl_xor(ps[rr], m);
        }
        if (lane < 32) {
            #pragma unroll
            for (int rr = 0; rr < 4; rr++) {
                p8w[(hc + rr) * 40 + l15] = (unsigned short)cvtpk(pA[rr], 0.f);
                p8w[(hc + rr) * 40 + 16 + l15] = (unsigned short)cvtpk(pB[rr], 0.f);
            }
        }
        #pragma unroll
        for (int rr = 0; rr < 4; rr++) {
            l_run[rr] = l_run[rr] * sc[rr] + ps[rr];
            m_run[rr] = mnew[rr];
        }
        // ---- PV MFMA (K = 32 j's), online rescale
        {
            #pragma unroll
            for (int ob = 0; ob < 4; ob++)
                #pragma unroll
                for (int rr = 0; rr < 4; rr++) acc[ob][rr] *= sc[rr];
            bf16x8 ap = *(const bf16x8*)(p8w + l15 * 40 + ecol);
            #pragma unroll
            for (int ob = 0; ob < 4; ob++) {
                bf16x8 bv = *(const bf16x8*)(svtw + (ob * 16 + l15) * 40 + ecol);
                acc[ob] = MFMA(ap, bv, acc[ob]);
            }
        }
        // ---- cooperative P write for this 32-j chunk
        {
            int hh = lane >> 3, jj = (lane & 7) * 4;
            uint2 pv2 = *(const uint2*)(p8w + hh * 40 + jj);
            *(uint2*)(P + ((long)hh << 20) + (long)i * 1024 + jt + jj) = pv2;
        }
        // ---- Mt record (chunk32 index = w*8+it)
        if (l15 == 0 && l4 < 2) {
            #pragma unroll
            for (int rr = 0; rr < 4; rr++)
                Mt[(i * 8 + hc + rr) * 32 + w * 8 + it] = mnew[rr];
        }
    }

    // ================= epilogue: merge the 4 waves =================
    if (l15 == 0 && l4 < 2) {
        #pragma unroll
        for (int rr = 0; rr < 4; rr++) {
            s_mw[w * 8 + hc + rr] = m_run[rr];
            s_lw[w * 8 + hc + rr] = l_run[rr];
        }
    }
    __syncthreads();
    float mf[4], lf[4];
    #pragma unroll
    for (int rr = 0; rr < 4; rr++) {
        int h = hc + rr;
        float m0 = fmaxf(fmaxf(s_mw[h], s_mw[8 + h]), fmaxf(s_mw[16 + h], s_mw[24 + h]));
        float ls = s_lw[h] * __expf(s_mw[h] - m0) + s_lw[8 + h] * __expf(s_mw[8 + h] - m0)
                 + s_lw[16 + h] * __expf(s_mw[16 + h] - m0) + s_lw[24 + h] * __expf(s_mw[24 + h] - m0);
        mf[rr] = m0; lf[rr] = ls;
    }
    float* obuf = (float*)&s_svt[0][0];
    if (l4 < 2) {
        #pragma unroll
        for (int ob = 0; ob < 4; ob++)
            #pragma unroll
            for (int rr = 0; rr < 4; rr++)
                obuf[w * 512 + (hc + rr) * 64 + ob * 16 + l15] =
                    acc[ob][rr] * __expf(m_run[rr] - mf[rr]);
    }
    if (w == 0 && l15 == 0 && l4 < 2) {
        #pragma unroll
        for (int rr = 0; rr < 4; rr++) { s_mf[hc + rr] = mf[rr]; s_lf[hc + rr] = lf[rr]; }
    }
    __syncthreads();
    #pragma unroll
    for (int e = 0; e < 2; e++) {
        int idx = t + e * 256;
        int hh = idx >> 6, dd = idx & 63;
        float v = obuf[idx] + obuf[512 + idx] + obuf[1024 + idx] + obuf[1536 + idx];
        outs[i * 512 + idx] = v / s_lf[hh] + bsv[dd];
    }
    if (t < 8) { Ml[(i * 8 + t) * 2] = s_mf[t]; Ml[(i * 8 + t) * 2 + 1] = s_lf[t]; }
}

// ---------------------------------------------------------------------------
// K4: node PV with per-32j-chunk correction (unchanged)
// ---------------------------------------------------------------------------
__global__ __launch_bounds__(256) void k_pv(
    const unsigned short* __restrict__ P, const unsigned short* __restrict__ vt,
    const float* __restrict__ Mt, const float* __restrict__ Ml,
    const float* __restrict__ outs, unsigned short* __restrict__ attn_bf)
{
    const int h = blockIdx.y;
    const int i0 = blockIdx.x * 16;
    const int t = threadIdx.x, lane = t & 63, jw = t >> 6;
    const int l15 = lane & 15, l4 = lane >> 4;
    __shared__ float s_f[16 * 32];
    __shared__ float s_acc[4][64][17];
    #pragma unroll
    for (int e = 0; e < 2; e++) {
        int idx = t + e * 256;
        int row = idx >> 5, c = idx & 31;
        float m = Ml[((i0 + row) * 8 + h) * 2];
        float l = Ml[((i0 + row) * 8 + h) * 2 + 1];
        s_f[row * 32 + c] = __expf(Mt[((i0 + row) * 8 + h) * 32 + c] - m) / l;
    }
    __syncthreads();
    const unsigned short* Ph = P + ((long)h << 20);
    const unsigned short* vh = vt + h * 65536;
    f32x4 acc[4] = {};
    for (int c8 = 0; c8 < 8; c8++) {
        const int c = jw * 8 + c8;
        bf16x8 a = *(const bf16x8*)(Ph + (i0 + l15) * 1024 + c * 32 + l4 * 8);
        #pragma unroll
        for (int ob = 0; ob < 4; ob++) {
            bf16x8 b = *(const bf16x8*)(vh + (ob * 16 + l15) * 1024 + c * 32 + l4 * 8);
            f32x4 zz; zz[0] = zz[1] = zz[2] = zz[3] = 0.f;
            f32x4 at = MFMA(a, b, zz);
            #pragma unroll
            for (int rr = 0; rr < 4; rr++)
                acc[ob][rr] = fmaf(s_f[(l4 * 4 + rr) * 32 + c], at[rr], acc[ob][rr]);
        }
    }
    #pragma unroll
    for (int ob = 0; ob < 4; ob++)
        #pragma unroll
        for (int rr = 0; rr < 4; rr++)
            s_acc[jw][lane][ob * 4 + rr] = acc[ob][rr];
    __syncthreads();
    #pragma unroll
    for (int rr = 0; rr < 4; rr++) {
        float sum = s_acc[0][lane][jw * 4 + rr] + s_acc[1][lane][jw * 4 + rr]
                  + s_acc[2][lane][jw * 4 + rr] + s_acc[3][lane][jw * 4 + rr];
        int ii = i0 + l4 * 4 + rr;
        int col = h * 64 + jw * 16 + l15;
        attn_bf[ii * 512 + col] = f2bf(sum + outs[ii * 512 + col]);
    }
}

// ---------------------------------------------------------------------------
// K5: output projection + bias + relu + residual (unchanged)
// ---------------------------------------------------------------------------
__global__ __launch_bounds__(256) void k_out(
    const unsigned short* __restrict__ attn_bf, const float* __restrict__ Wo,
    const float* __restrict__ bo, const float* __restrict__ nodes,
    float* __restrict__ z)
{
    const int i0 = blockIdx.x * 64, n0 = blockIdx.y * 64;
    const int t = threadIdx.x, lane = t & 63, w = t >> 6;
    const int l15 = lane & 15, l4 = lane >> 4;
    __shared__ __align__(16) unsigned short sA[64 * 72];
    __shared__ __align__(16) unsigned short sB[64 * 72];
    f32x4 acc[2][2] = {};
    const int wr = (w >> 1) * 32, wc = (w & 1) * 32;
    const int r = t >> 2, q4 = t & 3;
    for (int kb = 0; kb < 512; kb += 64) {
        for (int k = 0; k < 2; k++) {
            int col = k * 32 + q4 * 8;
            uint4 aa = *(const uint4*)(attn_bf + (i0 + r) * 512 + kb + col);
            *(uint4*)(sA + r * 72 + col) = aa;
        }
        for (int k = 0; k < 4; k++) {
            int col = k * 16 + q4 * 4;
            f32x4 bv_ = *(const f32x4*)(Wo + (n0 + r) * 512 + kb + col);
            uint2 pb; pb.x = pack2(bv_.x, bv_.y); pb.y = pack2(bv_.z, bv_.w);
            *(uint2*)(sB + r * 72 + col) = pb;
        }
        __syncthreads();
        for (int ks = 0; ks < 2; ks++) {
            bf16x8 a0 = *(const bf16x8*)(sA + (wr + l15) * 72 + ks * 32 + l4 * 8);
            bf16x8 a1 = *(const bf16x8*)(sA + (wr + 16 + l15) * 72 + ks * 32 + l4 * 8);
            bf16x8 b0 = *(const bf16x8*)(sB + (wc + l15) * 72 + ks * 32 + l4 * 8);
            bf16x8 b1 = *(const bf16x8*)(sB + (wc + 16 + l15) * 72 + ks * 32 + l4 * 8);
            acc[0][0] = MFMA(a0, b0, acc[0][0]);
            acc[0][1] = MFMA(a0, b1, acc[0][1]);
            acc[1][0] = MFMA(a1, b0, acc[1][0]);
            acc[1][1] = MFMA(a1, b1, acc[1][1]);
        }
        __syncthreads();
    }
    for (int fi = 0; fi < 2; fi++) for (int fj = 0; fj < 2; fj++)
        for (int rr = 0; rr < 4; rr++) {
            int i = i0 + wr + fi * 16 + l4 * 4 + rr;
            int n = n0 + wc + fj * 16 + l15;
            float v = fmaxf(acc[fi][fj][rr] + bo[n], 0.f);
            z[i * 512 + n] = nodes[i * 512 + n] + v;
        }
}

// ---------------------------------------------------------------------------
// K6: final LayerNorm (unchanged)
// ---------------------------------------------------------------------------
__global__ __launch_bounds__(256) void k_ln(
    const float* __restrict__ z, const float* __restrict__ g,
    const float* __restrict__ b, float* __restrict__ out)
{
    const int row = blockIdx.x * 4 + (threadIdx.x >> 6);
    const int lane = threadIdx.x & 63;
    const float* zp = z + row * 512;
    f32x4 x0 = *(const f32x4*)(zp + lane * 4);
    f32x4 x1 = *(const f32x4*)(zp + 256 + lane * 4);
    float s = x0.x + x0.y + x0.z + x0.w + x1.x + x1.y + x1.z + x1.w;
    float ss = x0.x * x0.x + x0.y * x0.y + x0.z * x0.z + x0.w * x0.w
             + x1.x * x1.x + x1.y * x1.y + x1.z * x1.z + x1.w * x1.w;
    for (int m = 1; m < 64; m <<= 1) { s += __shfl_xor(s, m); ss += __shfl_xor(ss, m); }
    float mean = s * (1.f / 512.f);
    float var = ss * (1.f / 512.f) - mean * mean;
    float rs = rsqrtf(var + 1e-5f);
    f32x4 g0 = *(const f32x4*)(g + lane * 4);
    f32x4 g1 = *(const f32x4*)(g + 256 + lane * 4);
    f32x4 b0 = *(const f32x4*)(b + lane * 4);
    f32x4 b1 = *(const f32x4*)(b + 256 + lane * 4);
    f32x4 o0, o1;
    o0.x = (x0.x - mean) * rs * g0.x + b0.x;
    o0.y = (x0.y - mean) * rs * g0.y + b0.y;
    o0.z = (x0.z - mean) * rs * g0.z + b0.z;
    o0.w = (x0.w - mean) * rs * g0.w + b0.w;
    o1.x = (x1.x - mean) * rs * g1.x + b1.x;
    o1.y = (x1.y - mean) * rs * g1.y + b1.y;
    o1.z = (x1.z - mean) * rs * g1.z + b1.z;
    o1.w = (x1.w - mean) * rs * g1.w + b1.w;
    *(f32x4*)(out + row * 512 + lane * 4) = o0;
    *(f32x4*)(out + row * 512 + 256 + lane * 4) = o1;
}

// ---------------------------------------------------------------------------
extern "C" void kernel_launch(void* const* d_in, const int* in_sizes, int n_in,
                              void* d_out, int out_size, void* d_ws, size_t ws_size,
                              hipStream_t stream)
{
    const float* nodes = (const float*)d_in[0];
    const float* edges = (const float*)d_in[1];
    const int* mask = (const int*)d_in[2];
    const float* Wq = (const float*)d_in[3]; const float* bq = (const float*)d_in[4];
    const float* Wk = (const float*)d_in[5]; const float* bk = (const float*)d_in[6];
    const float* Wv = (const float*)d_in[7]; const float* bv = (const float*)d_in[8];
    const float* Wsk = (const float*)d_in[9]; const float* bsk = (const float*)d_in[10];
    const float* Wsv = (const float*)d_in[11]; const float* bsv = (const float*)d_in[12];
    const float* Wo = (const float*)d_in[13]; const float* bo = (const float*)d_in[14];
    const float* png = (const float*)d_in[15]; const float* pnb = (const float*)d_in[16];
    const float* lng = (const float*)d_in[17]; const float* lnb = (const float*)d_in[18];
    float* out = (float*)d_out;

    char* ws = (char*)d_ws;
    unsigned short* qbf = (unsigned short*)(ws + 0);                 // 1 MB
    unsigned short* kbf = (unsigned short*)(ws + (1u << 20));        // 1 MB
    unsigned short* vt = (unsigned short*)(ws + (2u << 20));         // 1 MB
    unsigned short* U = (unsigned short*)(ws + (3u << 20));          // 1 MB
    float* S = (float*)(ws + (4u << 20));                            // 32 MB
    unsigned short* P = (unsigned short*)(ws + (36u << 20));         // 16 MB
    float* Mt = (float*)(ws + (52u << 20));                          // 1 MB
    float* Ml = (float*)(ws + (53u << 20));                          // 64 KB
    float* outs = (float*)(ws + (54u << 20));                        // 2 MB
    unsigned short* attn_bf = (unsigned short*)(ws + (56u << 20));   // 1 MB
    float* z = (float*)(ws + (57u << 20));                           // 2 MB

    k_qkv<<<dim3(16, 8, 3), 256, 0, stream>>>(nodes, Wq, bq, Wk, bk, Wv, bv,
                                              qbf, kbf, vt);
    k_u<<<dim3(16, 8), 256, 0, stream>>>(qbf, Wsk, U);
    k_scores<<<dim3(16, 16, 8), 256, 0, stream>>>(qbf, kbf, S);
    k_attn<<<dim3(1024), 256, 0, stream>>>(edges, mask, S, qbf, U, bsk,
                                           Wsv, bsv, png, pnb, P, Mt, Ml, outs);
    k_pv<<<dim3(64, 8), 256, 0, stream>>>(P, vt, Mt, Ml, outs, attn_bf);
    k_out<<<dim3(16, 8), 256, 0, stream>>>(attn_bf, Wo, bo, nodes, z);
    k_ln<<<dim3(256), 256, 0, stream>>>(z, lng, lnb, out);
}

// Round 10
// 132.842 us; speedup vs baseline: 1.1425x; 1.1425x over previous
//
#include <hip/hip_runtime.h>

using f32x4 = __attribute__((ext_vector_type(4))) float;
using f32x2 = __attribute__((ext_vector_type(2))) float;
using bf16x8 = __attribute__((ext_vector_type(8))) short;

#define MFMA(a, b, c) __builtin_amdgcn_mfma_f32_16x16x32_bf16(a, b, c, 0, 0, 0)

__device__ __forceinline__ unsigned short f2bf(float f) {
    union { float f; unsigned u; } c; c.f = f;
    unsigned u = c.u;
    u += 0x7fffu + ((u >> 16) & 1u);
    return (unsigned short)(u >> 16);
}
__device__ __forceinline__ float bf2f(unsigned short s) {
    union { unsigned u; float f; } c; c.u = ((unsigned)s) << 16; return c.f;
}
// HW packed f32x2 -> bf16x2 (RNE)
__device__ __forceinline__ unsigned cvtpk(float lo, float hi) {
    unsigned r;
    asm("v_cvt_pk_bf16_f32 %0, %1, %2" : "=v"(r) : "v"(lo), "v"(hi));
    return r;
}
__device__ __forceinline__ unsigned pack2(float a, float b) { return cvtpk(a, b); }
__device__ __forceinline__ bf16x8 pk8(f32x4 a, f32x4 b) {
    union { unsigned u[4]; bf16x8 v; } r;
    r.u[0] = cvtpk(a[0], a[1]); r.u[1] = cvtpk(a[2], a[3]);
    r.u[2] = cvtpk(b[0], b[1]); r.u[3] = cvtpk(b[2], b[3]);
    return r.v;
}

// ---------------------------------------------------------------------------
// K1: q/k/v projections. q scaled 0.125. q,k -> bf16 [1024][512]; v -> vt.
// ---------------------------------------------------------------------------
__global__ __launch_bounds__(256) void k_qkv(
    const float* __restrict__ nodes,
    const float* __restrict__ Wq, const float* __restrict__ bq,
    const float* __restrict__ Wk, const float* __restrict__ bk,
    const float* __restrict__ Wv, const float* __restrict__ bv,
    unsigned short* __restrict__ qbf, unsigned short* __restrict__ kbf,
    unsigned short* __restrict__ vt)
{
    const int kind = blockIdx.z;
    const float* W = (kind == 0) ? Wq : ((kind == 1) ? Wk : Wv);
    const float* bias = (kind == 0) ? bq : ((kind == 1) ? bk : bv);
    const int i0 = blockIdx.x * 64, n0 = blockIdx.y * 64;
    const int t = threadIdx.x, lane = t & 63, w = t >> 6;
    const int l15 = lane & 15, l4 = lane >> 4;
    __shared__ __align__(16) unsigned short sA[64 * 72];
    __shared__ __align__(16) unsigned short sB[64 * 72];
    f32x4 acc[2][2] = {};
    const int wr = (w >> 1) * 32, wc = (w & 1) * 32;
    const int r = t >> 2, q4 = t & 3;
    for (int kb = 0; kb < 512; kb += 64) {
        for (int k = 0; k < 4; k++) {
            int col = k * 16 + q4 * 4;
            f32x4 av = *(const f32x4*)(nodes + (i0 + r) * 512 + kb + col);
            f32x4 bv_ = *(const f32x4*)(W + (n0 + r) * 512 + kb + col);
            uint2 pa; pa.x = pack2(av.x, av.y); pa.y = pack2(av.z, av.w);
            uint2 pb; pb.x = pack2(bv_.x, bv_.y); pb.y = pack2(bv_.z, bv_.w);
            *(uint2*)(sA + r * 72 + col) = pa;
            *(uint2*)(sB + r * 72 + col) = pb;
        }
        __syncthreads();
        for (int ks = 0; ks < 2; ks++) {
            bf16x8 a0 = *(const bf16x8*)(sA + (wr + l15) * 72 + ks * 32 + l4 * 8);
            bf16x8 a1 = *(const bf16x8*)(sA + (wr + 16 + l15) * 72 + ks * 32 + l4 * 8);
            bf16x8 b0 = *(const bf16x8*)(sB + (wc + l15) * 72 + ks * 32 + l4 * 8);
            bf16x8 b1 = *(const bf16x8*)(sB + (wc + 16 + l15) * 72 + ks * 32 + l4 * 8);
            acc[0][0] = MFMA(a0, b0, acc[0][0]);
            acc[0][1] = MFMA(a0, b1, acc[0][1]);
            acc[1][0] = MFMA(a1, b0, acc[1][0]);
            acc[1][1] = MFMA(a1, b1, acc[1][1]);
        }
        __syncthreads();
    }
    const float scale = (kind == 0) ? 0.125f : 1.0f;
    for (int fi = 0; fi < 2; fi++) for (int fj = 0; fj < 2; fj++)
        for (int rr = 0; rr < 4; rr++) {
            int i = i0 + wr + fi * 16 + l4 * 4 + rr;
            int n = n0 + wc + fj * 16 + l15;
            float v = (acc[fi][fj][rr] + bias[n]) * scale;
            if (kind == 0) qbf[i * 512 + n] = f2bf(v);
            else if (kind == 1) kbf[i * 512 + n] = f2bf(v);
            else vt[n * 1024 + i] = f2bf(v);
        }
}

// ---------------------------------------------------------------------------
// K1b: U[i][h*64+e] = sum_d q[i][h*64+d] * Wsk[d][e]   (bf16 out)
// ---------------------------------------------------------------------------
__global__ __launch_bounds__(256) void k_u(
    const unsigned short* __restrict__ qbf, const float* __restrict__ Wsk,
    unsigned short* __restrict__ U)
{
    const int i0 = blockIdx.x * 64, h = blockIdx.y;
    const int t = threadIdx.x, lane = t & 63, w = t >> 6;
    const int l15 = lane & 15, l4 = lane >> 4;
    __shared__ __align__(16) unsigned short sQ[64 * 72];
    __shared__ __align__(16) unsigned short sWT[64 * 72];   // Wsk^T bf16 [e][d]
    {
        const int r = t >> 2, c0 = (t & 3) * 16;
        *(uint4*)(sQ + r * 72 + c0) = *(const uint4*)(qbf + (i0 + r) * 512 + h * 64 + c0);
        *(uint4*)(sQ + r * 72 + c0 + 8) = *(const uint4*)(qbf + (i0 + r) * 512 + h * 64 + c0 + 8);
        #pragma unroll
        for (int e = 0; e < 16; e++)
            sWT[(c0 + e) * 72 + r] = f2bf(Wsk[r * 64 + c0 + e]);
    }
    __syncthreads();
    bf16x8 b0 = *(const bf16x8*)(sWT + (w * 16 + l15) * 72 + l4 * 8);
    bf16x8 b1 = *(const bf16x8*)(sWT + (w * 16 + l15) * 72 + 32 + l4 * 8);
    for (int fb = 0; fb < 4; fb++) {
        bf16x8 a0 = *(const bf16x8*)(sQ + (fb * 16 + l15) * 72 + l4 * 8);
        bf16x8 a1 = *(const bf16x8*)(sQ + (fb * 16 + l15) * 72 + 32 + l4 * 8);
        f32x4 acc; acc[0] = acc[1] = acc[2] = acc[3] = 0.f;
        acc = MFMA(a0, b0, acc); acc = MFMA(a1, b1, acc);
        #pragma unroll
        for (int rr = 0; rr < 4; rr++)
            U[(i0 + fb * 16 + l4 * 4 + rr) * 512 + h * 64 + w * 16 + l15] = f2bf(acc[rr]);
    }
}

// ---------------------------------------------------------------------------
// K2: node-node scores S[h][i][j] (unchanged)
// ---------------------------------------------------------------------------
__global__ __launch_bounds__(256) void k_scores(
    const unsigned short* __restrict__ qbf, const unsigned short* __restrict__ kbf,
    float* __restrict__ S)
{
    const int h = blockIdx.z, i0 = blockIdx.x * 64, j0 = blockIdx.y * 64;
    const int t = threadIdx.x, lane = t & 63, w = t >> 6;
    const int l15 = lane & 15, l4 = lane >> 4;
    __shared__ __align__(16) unsigned short sQ[64 * 72];
    __shared__ __align__(16) unsigned short sK[64 * 72];
    const int r = t >> 2, q4 = t & 3;
    for (int k = 0; k < 2; k++) {
        int col = k * 32 + q4 * 8;
        uint4 aq = *(const uint4*)(qbf + (i0 + r) * 512 + h * 64 + col);
        uint4 ak = *(const uint4*)(kbf + (j0 + r) * 512 + h * 64 + col);
        *(uint4*)(sQ + r * 72 + col) = aq;
        *(uint4*)(sK + r * 72 + col) = ak;
    }
    __syncthreads();
    f32x4 acc[2][2] = {};
    const int wr = (w >> 1) * 32, wc = (w & 1) * 32;
    for (int ks = 0; ks < 2; ks++) {
        bf16x8 a0 = *(const bf16x8*)(sQ + (wr + l15) * 72 + ks * 32 + l4 * 8);
        bf16x8 a1 = *(const bf16x8*)(sQ + (wr + 16 + l15) * 72 + ks * 32 + l4 * 8);
        bf16x8 b0 = *(const bf16x8*)(sK + (wc + l15) * 72 + ks * 32 + l4 * 8);
        bf16x8 b1 = *(const bf16x8*)(sK + (wc + 16 + l15) * 72 + ks * 32 + l4 * 8);
        acc[0][0] = MFMA(a0, b0, acc[0][0]);
        acc[0][1] = MFMA(a0, b1, acc[0][1]);
        acc[1][0] = MFMA(a1, b0, acc[1][0]);
        acc[1][1] = MFMA(a1, b1, acc[1][1]);
    }
    for (int fi = 0; fi < 2; fi++) for (int fj = 0; fj < 2; fj++)
        for (int rr = 0; rr < 4; rr++) {
            long i = i0 + wr + fi * 16 + l4 * 4 + rr;
            int j = j0 + wc + fj * 16 + l15;
            S[((long)h << 20) + i * 1024 + j] = acc[fi][fj][rr];
        }
}

// ---------------------------------------------------------------------------
// K3 v10: barrier-free fused attention core + SOFTWARE PIPELINE.
// Next iteration's edge/S/mask loads are issued exactly where the current
// iteration's f32 edge registers die (after the LN pack) so HBM latency
// hides under the score/sv/softmax/PV section. Register-lifetime neutral.
// ---------------------------------------------------------------------------
__global__ __launch_bounds__(256) void k_attn(
    const float* __restrict__ edges, const int* __restrict__ maskp,
    const float* __restrict__ S, const unsigned short* __restrict__ qbf,
    const unsigned short* __restrict__ Ubf,
    const float* __restrict__ bsk, const float* __restrict__ Wsv,
    const float* __restrict__ bsv,
    const float* __restrict__ png, const float* __restrict__ pnb,
    unsigned short* __restrict__ P, float* __restrict__ Mt,
    float* __restrict__ Ml, float* __restrict__ outs)
{
    const int i = blockIdx.x;
    const int t = threadIdx.x;
    const int lane = t & 63, w = t >> 6;
    const int l15 = lane & 15, l4 = lane >> 4;
    const int ecol = l4 * 8;

    __shared__ __align__(16) unsigned short s_wsv[64 * 72];   // 9216 B
    __shared__ __align__(16) unsigned short s_svt[4][64 * 40];// 20480 B
    __shared__ __align__(16) unsigned short s_p8[4][16 * 40]; // 5120 B
    __shared__ float s_g[64], s_b[64];                        // 512 B
    __shared__ float s_mw[32], s_lw[32], s_mf[8], s_lf[8], s_qbsk[8];

    unsigned short* svtw = s_svt[w];
    unsigned short* p8w = s_p8[w];

    // ---- stage Wsv as bf16 in LDS; LN params as f32 in LDS
    {
        const int row = t >> 2, c0 = (t & 3) * 16;
        const float* pv = Wsv + row * 64 + c0;
        uint2 w0, w1;
        w0.x = pack2(pv[0], pv[1]);  w0.y = pack2(pv[2], pv[3]);
        w1.x = pack2(pv[4], pv[5]);  w1.y = pack2(pv[6], pv[7]);
        *(uint2*)(s_wsv + row * 72 + c0) = w0;
        *(uint2*)(s_wsv + row * 72 + c0 + 4) = w1;
        w0.x = pack2(pv[8], pv[9]);  w0.y = pack2(pv[10], pv[11]);
        w1.x = pack2(pv[12], pv[13]); w1.y = pack2(pv[14], pv[15]);
        *(uint2*)(s_wsv + row * 72 + c0 + 8) = w0;
        *(uint2*)(s_wsv + row * 72 + c0 + 12) = w1;
    }
    if (t < 64) { s_g[t] = png[t]; s_b[t] = pnb[t]; }
    // ---- zero p8 rows 8-15 of every wave buffer (never rewritten)
    {
        int wb = t >> 6, rem = t & 63;
        int row = 8 + (rem >> 3), c4 = (rem & 7) * 4;
        uint2 z; z.x = 0; z.y = 0;
        *(uint2*)(&s_p8[wb][row * 40 + c4]) = z;
    }
    if (t < 8) {
        float a = 0.f;
        for (int d = 0; d < 64; d++) a += bf2f(qbf[i * 512 + t * 64 + d]) * bsk[d];
        s_qbsk[t] = a;
    }

    // ---- U A-fragment: rows = heads (l15<8), rows 8-15 zero
    bf16x8 aU0 = {}, aU1 = {};
    if (l15 < 8) {
        aU0 = *(const bf16x8*)(Ubf + i * 512 + l15 * 64 + ecol);
        aU1 = *(const bf16x8*)(Ubf + i * 512 + l15 * 64 + 32 + ecol);
    }

    __syncthreads();   // weights / LN params / p8-zeros / qbsk visible

    const int hc = (l4 & 1) * 4;   // this lane's 4 heads (lanes 32-63 mirror)
    float qb[4];
    #pragma unroll
    for (int rr = 0; rr < 4; rr++) qb[rr] = s_qbsk[hc + rr];

    const float* erow = edges + (long)i * 65536;
    f32x4 m_run, l_run;
    #pragma unroll
    for (int rr = 0; rr < 4; rr++) { m_run[rr] = -1e30f; l_run[rr] = 0.f; }
    f32x4 acc[4] = {};

    // ---- prologue: load iteration 0's edge fragments, S, mask
    const float* pa0 = erow + (w * 256 + l15) * 64 + ecol;
    f32x4 ea0 = *(const f32x4*)(pa0);
    f32x4 ea1 = *(const f32x4*)(pa0 + 4);
    f32x4 ea2 = *(const f32x4*)(pa0 + 32);
    f32x4 ea3 = *(const f32x4*)(pa0 + 36);
    f32x4 eb0 = *(const f32x4*)(pa0 + 1024);
    f32x4 eb1 = *(const f32x4*)(pa0 + 1028);
    f32x4 eb2 = *(const f32x4*)(pa0 + 1056);
    f32x4 eb3 = *(const f32x4*)(pa0 + 1060);
    float Sva[4], Svb[4];
    #pragma unroll
    for (int rr = 0; rr < 4; rr++) {
        Sva[rr] = S[((long)(hc + rr) << 20) + (long)i * 1024 + w * 256 + l15];
        Svb[rr] = S[((long)(hc + rr) << 20) + (long)i * 1024 + w * 256 + 16 + l15];
    }
    int mka = maskp[i * 1024 + w * 256 + l15];
    int mkb = maskp[i * 1024 + w * 256 + 16 + l15];

    for (int it = 0; it < 8; it++) {
        const int jt = w * 256 + it * 32;
        const float* pnxt = erow + (jt + 32 + l15) * 64 + ecol;

        f32x4 ca, cb;
        bf16x8 xA0, xA1, xB0, xB1;
        f32x4 na0, na1, na2, na3, nb0, nb1, nb2, nb3;
        float nSa[4], nSb[4]; int nma = 0, nmb = 0;

        // ===== half A LN (consumes ea*) =====
        {
            float s1 = 0.f, s2 = 0.f;
            #pragma unroll
            for (int q = 0; q < 4; q++) {
                s1 += ea0[q] + ea1[q] + ea2[q] + ea3[q];
                s2 += ea0[q]*ea0[q] + ea1[q]*ea1[q] + ea2[q]*ea2[q] + ea3[q]*ea3[q];
            }
            s1 += __shfl_xor(s1, 16); s2 += __shfl_xor(s2, 16);
            s1 += __shfl_xor(s1, 32); s2 += __shfl_xor(s2, 32);
            const float mean = s1 * (1.f / 64.f);
            const float var = s2 * (1.f / 64.f) - mean * mean;
            const float rs = rsqrtf(var + 1e-5f);
            const f32x4 g0 = *(const f32x4*)(s_g + ecol);
            const f32x4 g1 = *(const f32x4*)(s_g + ecol + 4);
            const f32x4 g2 = *(const f32x4*)(s_g + 32 + ecol);
            const f32x4 g3 = *(const f32x4*)(s_g + 36 + ecol);
            const f32x4 b0_ = *(const f32x4*)(s_b + ecol);
            const f32x4 b1_ = *(const f32x4*)(s_b + ecol + 4);
            const f32x4 b2_ = *(const f32x4*)(s_b + 32 + ecol);
            const f32x4 b3_ = *(const f32x4*)(s_b + 36 + ecol);
            f32x4 y0, y1, y2, y3;
            #pragma unroll
            for (int q = 0; q < 4; q++) {
                y0[q] = (ea0[q] - mean) * rs * g0[q] + b0_[q];
                y1[q] = (ea1[q] - mean) * rs * g1[q] + b1_[q];
                y2[q] = (ea2[q] - mean) * rs * g2[q] + b2_[q];
                y3[q] = (ea3[q] - mean) * rs * g3[q] + b3_[q];
            }
            xA0 = pk8(y0, y1); xA1 = pk8(y2, y3);
        }
        // ---- PREFETCH next iter half A (ea* now dead) + S/mask ----
        if (it < 7) {
            na0 = *(const f32x4*)(pnxt);
            na1 = *(const f32x4*)(pnxt + 4);
            na2 = *(const f32x4*)(pnxt + 32);
            na3 = *(const f32x4*)(pnxt + 36);
            const int njA = jt + 32 + l15, njB = njA + 16;
            #pragma unroll
            for (int rr = 0; rr < 4; rr++) {
                nSa[rr] = S[((long)(hc + rr) << 20) + (long)i * 1024 + njA];
                nSb[rr] = S[((long)(hc + rr) << 20) + (long)i * 1024 + njB];
            }
            nma = maskp[i * 1024 + njA];
            nmb = maskp[i * 1024 + njB];
        }
        // ===== half B LN (consumes eb*) =====
        {
            float s1 = 0.f, s2 = 0.f;
            #pragma unroll
            for (int q = 0; q < 4; q++) {
                s1 += eb0[q] + eb1[q] + eb2[q] + eb3[q];
                s2 += eb0[q]*eb0[q] + eb1[q]*eb1[q] + eb2[q]*eb2[q] + eb3[q]*eb3[q];
            }
            s1 += __shfl_xor(s1, 16); s2 += __shfl_xor(s2, 16);
            s1 += __shfl_xor(s1, 32); s2 += __shfl_xor(s2, 32);
            const float mean = s1 * (1.f / 64.f);
            const float var = s2 * (1.f / 64.f) - mean * mean;
            const float rs = rsqrtf(var + 1e-5f);
            const f32x4 g0 = *(const f32x4*)(s_g + ecol);
            const f32x4 g1 = *(const f32x4*)(s_g + ecol + 4);
            const f32x4 g2 = *(const f32x4*)(s_g + 32 + ecol);
            const f32x4 g3 = *(const f32x4*)(s_g + 36 + ecol);
            const f32x4 b0_ = *(const f32x4*)(s_b + ecol);
            const f32x4 b1_ = *(const f32x4*)(s_b + ecol + 4);
            const f32x4 b2_ = *(const f32x4*)(s_b + 32 + ecol);
            const f32x4 b3_ = *(const f32x4*)(s_b + 36 + ecol);
            f32x4 y0, y1, y2, y3;
            #pragma unroll
            for (int q = 0; q < 4; q++) {
                y0[q] = (eb0[q] - mean) * rs * g0[q] + b0_[q];
                y1[q] = (eb1[q] - mean) * rs * g1[q] + b1_[q];
                y2[q] = (eb2[q] - mean) * rs * g2[q] + b2_[q];
                y3[q] = (eb3[q] - mean) * rs * g3[q] + b3_[q];
            }
            xB0 = pk8(y0, y1); xB1 = pk8(y2, y3);
        }
        // ---- PREFETCH next iter half B (eb* now dead) ----
        if (it < 7) {
            nb0 = *(const f32x4*)(pnxt + 1024);
            nb1 = *(const f32x4*)(pnxt + 1028);
            nb2 = *(const f32x4*)(pnxt + 1056);
            nb3 = *(const f32x4*)(pnxt + 1060);
        }

        // ===== scores (struct score via U-fold; direct MFMA on x) =====
        ca[0] = ca[1] = ca[2] = ca[3] = 0.f;
        ca = MFMA(aU0, xA0, ca); ca = MFMA(aU1, xA1, ca);
        #pragma unroll
        for (int rr = 0; rr < 4; rr++)
            ca[rr] = mka ? (ca[rr] + Sva[rr] + qb[rr]) : -1e9f;
        cb[0] = cb[1] = cb[2] = cb[3] = 0.f;
        cb = MFMA(aU0, xB0, cb); cb = MFMA(aU1, xB1, cb);
        #pragma unroll
        for (int rr = 0; rr < 4; rr++)
            cb[rr] = mkb ? (cb[rr] + Svb[rr] + qb[rr]) : -1e9f;

        // ===== sv projection MFMAs -> svt (wave-local transpose) =====
        #pragma unroll
        for (int ob = 0; ob < 4; ob++) {
            bf16x8 wv0 = *(const bf16x8*)(s_wsv + (ob * 16 + l15) * 72 + ecol);
            bf16x8 wv1 = *(const bf16x8*)(s_wsv + (ob * 16 + l15) * 72 + 32 + ecol);
            f32x4 cvA; cvA[0] = cvA[1] = cvA[2] = cvA[3] = 0.f;
            cvA = MFMA(xA0, wv0, cvA); cvA = MFMA(xA1, wv1, cvA);
            f32x4 cvB; cvB[0] = cvB[1] = cvB[2] = cvB[3] = 0.f;
            cvB = MFMA(xB0, wv0, cvB); cvB = MFMA(xB1, wv1, cvB);
            const int jbA = l4 * 4, jbB = 16 + l4 * 4;
            *(unsigned*)(svtw + (ob * 16 + l15) * 40 + jbA) = pack2(cvA[0], cvA[1]);
            *(unsigned*)(svtw + (ob * 16 + l15) * 40 + jbA + 2) = pack2(cvA[2], cvA[3]);
            *(unsigned*)(svtw + (ob * 16 + l15) * 40 + jbB) = pack2(cvB[0], cvB[1]);
            *(unsigned*)(svtw + (ob * 16 + l15) * 40 + jbB + 2) = pack2(cvB[2], cvB[3]);
        }

        // ---- online softmax over this 32-j chunk (wave-local, shfl only)
        f32x4 mx;
        #pragma unroll
        for (int rr = 0; rr < 4; rr++) mx[rr] = fmaxf(ca[rr], cb[rr]);
        for (int m = 1; m < 16; m <<= 1) {
            #pragma unroll
            for (int rr = 0; rr < 4; rr++) mx[rr] = fmaxf(mx[rr], __shfl_xor(mx[rr], m));
        }
        f32x4 mnew, sc;
        #pragma unroll
        for (int rr = 0; rr < 4; rr++) {
            mnew[rr] = fmaxf(m_run[rr], mx[rr]);
            sc[rr] = __expf(m_run[rr] - mnew[rr]);
        }
        f32x4 pA, pB, ps;
        #pragma unroll
        for (int rr = 0; rr < 4; rr++) {
            pA[rr] = __expf(ca[rr] - mnew[rr]);
            pB[rr] = __expf(cb[rr] - mnew[rr]);
            ps[rr] = pA[rr] + pB[rr];
        }
        for (int m = 1; m < 16; m <<= 1) {
            #pragma unroll
            for (int rr = 0; rr < 4; rr++) ps[rr] += __shfl_xor(ps[rr], m);
        }
        if (lane < 32) {
            #pragma unroll
            for (int rr = 0; rr < 4; rr++) {
                p8w[(hc + rr) * 40 + l15] = (unsigned short)cvtpk(pA[rr], 0.f);
                p8w[(hc + rr) * 40 + 16 + l15] = (unsigned short)cvtpk(pB[rr], 0.f);
            }
        }
        #pragma unroll
        for (int rr = 0; rr < 4; rr++) {
            l_run[rr] = l_run[rr] * sc[rr] + ps[rr];
            m_run[rr] = mnew[rr];
        }
        // ---- PV MFMA (K = 32 j's), online rescale
        {
            #pragma unroll
            for (int ob = 0; ob < 4; ob++)
                #pragma unroll
                for (int rr = 0; rr < 4; rr++) acc[ob][rr] *= sc[rr];
            bf16x8 ap = *(const bf16x8*)(p8w + l15 * 40 + ecol);
            #pragma unroll
            for (int ob = 0; ob < 4; ob++) {
                bf16x8 bv = *(const bf16x8*)(svtw + (ob * 16 + l15) * 40 + ecol);
                acc[ob] = MFMA(ap, bv, acc[ob]);
            }
        }
        // ---- cooperative P write for this 32-j chunk
        {
            int hh = lane >> 3, jj = (lane & 7) * 4;
            uint2 pv2 = *(const uint2*)(p8w + hh * 40 + jj);
            *(uint2*)(P + ((long)hh << 20) + (long)i * 1024 + jt + jj) = pv2;
        }
        // ---- Mt record (chunk32 index = w*8+it)
        if (l15 == 0 && l4 < 2) {
            #pragma unroll
            for (int rr = 0; rr < 4; rr++)
                Mt[(i * 8 + hc + rr) * 32 + w * 8 + it] = mnew[rr];
        }
        // ---- rotate pipeline registers
        if (it < 7) {
            ea0 = na0; ea1 = na1; ea2 = na2; ea3 = na3;
            eb0 = nb0; eb1 = nb1; eb2 = nb2; eb3 = nb3;
            #pragma unroll
            for (int rr = 0; rr < 4; rr++) { Sva[rr] = nSa[rr]; Svb[rr] = nSb[rr]; }
            mka = nma; mkb = nmb;
        }
    }

    // ================= epilogue: merge the 4 waves =================
    if (l15 == 0 && l4 < 2) {
        #pragma unroll
        for (int rr = 0; rr < 4; rr++) {
            s_mw[w * 8 + hc + rr] = m_run[rr];
            s_lw[w * 8 + hc + rr] = l_run[rr];
        }
    }
    __syncthreads();
    float mf[4], lf[4];
    #pragma unroll
    for (int rr = 0; rr < 4; rr++) {
        int h = hc + rr;
        float m0 = fmaxf(fmaxf(s_mw[h], s_mw[8 + h]), fmaxf(s_mw[16 + h], s_mw[24 + h]));
        float ls = s_lw[h] * __expf(s_mw[h] - m0) + s_lw[8 + h] * __expf(s_mw[8 + h] - m0)
                 + s_lw[16 + h] * __expf(s_mw[16 + h] - m0) + s_lw[24 + h] * __expf(s_mw[24 + h] - m0);
        mf[rr] = m0; lf[rr] = ls;
    }
    float* obuf = (float*)&s_svt[0][0];
    if (l4 < 2) {
        #pragma unroll
        for (int ob = 0; ob < 4; ob++)
            #pragma unroll
            for (int rr = 0; rr < 4; rr++)
                obuf[w * 512 + (hc + rr) * 64 + ob * 16 + l15] =
                    acc[ob][rr] * __expf(m_run[rr] - mf[rr]);
    }
    if (w == 0 && l15 == 0 && l4 < 2) {
        #pragma unroll
        for (int rr = 0; rr < 4; rr++) { s_mf[hc + rr] = mf[rr]; s_lf[hc + rr] = lf[rr]; }
    }
    __syncthreads();
    #pragma unroll
    for (int e = 0; e < 2; e++) {
        int idx = t + e * 256;
        int hh = idx >> 6, dd = idx & 63;
        float v = obuf[idx] + obuf[512 + idx] + obuf[1024 + idx] + obuf[1536 + idx];
        outs[i * 512 + idx] = v / s_lf[hh] + bsv[dd];
    }
    if (t < 8) { Ml[(i * 8 + t) * 2] = s_mf[t]; Ml[(i * 8 + t) * 2 + 1] = s_lf[t]; }
}

// ---------------------------------------------------------------------------
// K4: node PV with per-32j-chunk correction (unchanged)
// ---------------------------------------------------------------------------
__global__ __launch_bounds__(256) void k_pv(
    const unsigned short* __restrict__ P, const unsigned short* __restrict__ vt,
    const float* __restrict__ Mt, const float* __restrict__ Ml,
    const float* __restrict__ outs, unsigned short* __restrict__ attn_bf)
{
    const int h = blockIdx.y;
    const int i0 = blockIdx.x * 16;
    const int t = threadIdx.x, lane = t & 63, jw = t >> 6;
    const int l15 = lane & 15, l4 = lane >> 4;
    __shared__ float s_f[16 * 32];
    __shared__ float s_acc[4][64][17];
    #pragma unroll
    for (int e = 0; e < 2; e++) {
        int idx = t + e * 256;
        int row = idx >> 5, c = idx & 31;
        float m = Ml[((i0 + row) * 8 + h) * 2];
        float l = Ml[((i0 + row) * 8 + h) * 2 + 1];
        s_f[row * 32 + c] = __expf(Mt[((i0 + row) * 8 + h) * 32 + c] - m) / l;
    }
    __syncthreads();
    const unsigned short* Ph = P + ((long)h << 20);
    const unsigned short* vh = vt + h * 65536;
    f32x4 acc[4] = {};
    for (int c8 = 0; c8 < 8; c8++) {
        const int c = jw * 8 + c8;
        bf16x8 a = *(const bf16x8*)(Ph + (i0 + l15) * 1024 + c * 32 + l4 * 8);
        #pragma unroll
        for (int ob = 0; ob < 4; ob++) {
            bf16x8 b = *(const bf16x8*)(vh + (ob * 16 + l15) * 1024 + c * 32 + l4 * 8);
            f32x4 zz; zz[0] = zz[1] = zz[2] = zz[3] = 0.f;
            f32x4 at = MFMA(a, b, zz);
            #pragma unroll
            for (int rr = 0; rr < 4; rr++)
                acc[ob][rr] = fmaf(s_f[(l4 * 4 + rr) * 32 + c], at[rr], acc[ob][rr]);
        }
    }
    #pragma unroll
    for (int ob = 0; ob < 4; ob++)
        #pragma unroll
        for (int rr = 0; rr < 4; rr++)
            s_acc[jw][lane][ob * 4 + rr] = acc[ob][rr];
    __syncthreads();
    #pragma unroll
    for (int rr = 0; rr < 4; rr++) {
        float sum = s_acc[0][lane][jw * 4 + rr] + s_acc[1][lane][jw * 4 + rr]
                  + s_acc[2][lane][jw * 4 + rr] + s_acc[3][lane][jw * 4 + rr];
        int ii = i0 + l4 * 4 + rr;
        int col = h * 64 + jw * 16 + l15;
        attn_bf[ii * 512 + col] = f2bf(sum + outs[ii * 512 + col]);
    }
}

// ---------------------------------------------------------------------------
// K5: output projection + bias + relu + residual (unchanged)
// ---------------------------------------------------------------------------
__global__ __launch_bounds__(256) void k_out(
    const unsigned short* __restrict__ attn_bf, const float* __restrict__ Wo,
    const float* __restrict__ bo, const float* __restrict__ nodes,
    float* __restrict__ z)
{
    const int i0 = blockIdx.x * 64, n0 = blockIdx.y * 64;
    const int t = threadIdx.x, lane = t & 63, w = t >> 6;
    const int l15 = lane & 15, l4 = lane >> 4;
    __shared__ __align__(16) unsigned short sA[64 * 72];
    __shared__ __align__(16) unsigned short sB[64 * 72];
    f32x4 acc[2][2] = {};
    const int wr = (w >> 1) * 32, wc = (w & 1) * 32;
    const int r = t >> 2, q4 = t & 3;
    for (int kb = 0; kb < 512; kb += 64) {
        for (int k = 0; k < 2; k++) {
            int col = k * 32 + q4 * 8;
            uint4 aa = *(const uint4*)(attn_bf + (i0 + r) * 512 + kb + col);
            *(uint4*)(sA + r * 72 + col) = aa;
        }
        for (int k = 0; k < 4; k++) {
            int col = k * 16 + q4 * 4;
            f32x4 bv_ = *(const f32x4*)(Wo + (n0 + r) * 512 + kb + col);
            uint2 pb; pb.x = pack2(bv_.x, bv_.y); pb.y = pack2(bv_.z, bv_.w);
            *(uint2*)(sB + r * 72 + col) = pb;
        }
        __syncthreads();
        for (int ks = 0; ks < 2; ks++) {
            bf16x8 a0 = *(const bf16x8*)(sA + (wr + l15) * 72 + ks * 32 + l4 * 8);
            bf16x8 a1 = *(const bf16x8*)(sA + (wr + 16 + l15) * 72 + ks * 32 + l4 * 8);
            bf16x8 b0 = *(const bf16x8*)(sB + (wc + l15) * 72 + ks * 32 + l4 * 8);
            bf16x8 b1 = *(const bf16x8*)(sB + (wc + 16 + l15) * 72 + ks * 32 + l4 * 8);
            acc[0][0] = MFMA(a0, b0, acc[0][0]);
            acc[0][1] = MFMA(a0, b1, acc[0][1]);
            acc[1][0] = MFMA(a1, b0, acc[1][0]);
            acc[1][1] = MFMA(a1, b1, acc[1][1]);
        }
        __syncthreads();
    }
    for (int fi = 0; fi < 2; fi++) for (int fj = 0; fj < 2; fj++)
        for (int rr = 0; rr < 4; rr++) {
            int i = i0 + wr + fi * 16 + l4 * 4 + rr;
            int n = n0 + wc + fj * 16 + l15;
            float v = fmaxf(acc[fi][fj][rr] + bo[n], 0.f);
            z[i * 512 + n] = nodes[i * 512 + n] + v;
        }
}

// ---------------------------------------------------------------------------
// K6: final LayerNorm (unchanged)
// ---------------------------------------------------------------------------
__global__ __launch_bounds__(256) void k_ln(
    const float* __restrict__ z, const float* __restrict__ g,
    const float* __restrict__ b, float* __restrict__ out)
{
    const int row = blockIdx.x * 4 + (threadIdx.x >> 6);
    const int lane = threadIdx.x & 63;
    const float* zp = z + row * 512;
    f32x4 x0 = *(const f32x4*)(zp + lane * 4);
    f32x4 x1 = *(const f32x4*)(zp + 256 + lane * 4);
    float s = x0.x + x0.y + x0.z + x0.w + x1.x + x1.y + x1.z + x1.w;
    float ss = x0.x * x0.x + x0.y * x0.y + x0.z * x0.z + x0.w * x0.w
             + x1.x * x1.x + x1.y * x1.y + x1.z * x1.z + x1.w * x1.w;
    for (int m = 1; m < 64; m <<= 1) { s += __shfl_xor(s, m); ss += __shfl_xor(ss, m); }
    float mean = s * (1.f / 512.f);
    float var = ss * (1.f / 512.f) - mean * mean;
    float rs = rsqrtf(var + 1e-5f);
    f32x4 g0 = *(const f32x4*)(g + lane * 4);
    f32x4 g1 = *(const f32x4*)(g + 256 + lane * 4);
    f32x4 b0 = *(const f32x4*)(b + lane * 4);
    f32x4 b1 = *(const f32x4*)(b + 256 + lane * 4);
    f32x4 o0, o1;
    o0.x = (x0.x - mean) * rs * g0.x + b0.x;
    o0.y = (x0.y - mean) * rs * g0.y + b0.y;
    o0.z = (x0.z - mean) * rs * g0.z + b0.z;
    o0.w = (x0.w - mean) * rs * g0.w + b0.w;
    o1.x = (x1.x - mean) * rs * g1.x + b1.x;
    o1.y = (x1.y - mean) * rs * g1.y + b1.y;
    o1.z = (x1.z - mean) * rs * g1.z + b1.z;
    o1.w = (x1.w - mean) * rs * g1.w + b1.w;
    *(f32x4*)(out + row * 512 + lane * 4) = o0;
    *(f32x4*)(out + row * 512 + 256 + lane * 4) = o1;
}

// ---------------------------------------------------------------------------
extern "C" void kernel_launch(void* const* d_in, const int* in_sizes, int n_in,
                              void* d_out, int out_size, void* d_ws, size_t ws_size,
                              hipStream_t stream)
{
    const float* nodes = (const float*)d_in[0];
    const float* edges = (const float*)d_in[1];
    const int* mask = (const int*)d_in[2];
    const float* Wq = (const float*)d_in[3]; const float* bq = (const float*)d_in[4];
    const float* Wk = (const float*)d_in[5]; const float* bk = (const float*)d_in[6];
    const float* Wv = (const float*)d_in[7]; const float* bv = (const float*)d_in[8];
    const float* Wsk = (const float*)d_in[9]; const float* bsk = (const float*)d_in[10];
    const float* Wsv = (const float*)d_in[11]; const float* bsv = (const float*)d_in[12];
    const float* Wo = (const float*)d_in[13]; const float* bo = (const float*)d_in[14];
    const float* png = (const float*)d_in[15]; const float* pnb = (const float*)d_in[16];
    const float* lng = (const float*)d_in[17]; const float* lnb = (const float*)d_in[18];
    float* out = (float*)d_out;

    char* ws = (char*)d_ws;
    unsigned short* qbf = (unsigned short*)(ws + 0);                 // 1 MB
    unsigned short* kbf = (unsigned short*)(ws + (1u << 20));        // 1 MB
    unsigned short* vt = (unsigned short*)(ws + (2u << 20));         // 1 MB
    unsigned short* U = (unsigned short*)(ws + (3u << 20));          // 1 MB
    float* S = (float*)(ws + (4u << 20));                            // 32 MB
    unsigned short* P = (unsigned short*)(ws + (36u << 20));         // 16 MB
    float* Mt = (float*)(ws + (52u << 20));                          // 1 MB
    float* Ml = (float*)(ws + (53u << 20));                          // 64 KB
    float* outs = (float*)(ws + (54u << 20));                        // 2 MB
    unsigned short* attn_bf = (unsigned short*)(ws + (56u << 20));   // 1 MB
    float* z = (float*)(ws + (57u << 20));                           // 2 MB

    k_qkv<<<dim3(16, 8, 3), 256, 0, stream>>>(nodes, Wq, bq, Wk, bk, Wv, bv,
                                              qbf, kbf, vt);
    k_u<<<dim3(16, 8), 256, 0, stream>>>(qbf, Wsk, U);
    k_scores<<<dim3(16, 16, 8), 256, 0, stream>>>(qbf, kbf, S);
    k_attn<<<dim3(1024), 256, 0, stream>>>(edges, mask, S, qbf, U, bsk,
                                           Wsv, bsv, png, pnb, P, Mt, Ml, outs);
    k_pv<<<dim3(64, 8), 256, 0, stream>>>(P, vt, Mt, Ml, outs, attn_bf);
    k_out<<<dim3(16, 8), 256, 0, stream>>>(attn_bf, Wo, bo, nodes, z);
    k_ln<<<dim3(256), 256, 0, stream>>>(z, lng, lnb, out);
}